// Round 5
// baseline (893.290 us; speedup 1.0000x reference)
//
#include <hip/hip_runtime.h>

#define BB 8
#define CC 256
#define KK 19
#define HWN 65536
#define H1 2048
#define H2 512
#define NC 38
#define NEG 0.2f
#define HWT 256            // hw per chunk (cam tile = 19*256*4 = 19456 B LDS)
#define NCHUNK 256         // chunks per image (HWN / HWT)

// ---------------- Stage 1: partial[slice][b][k][c] = sum_{hw in slice} cam*x ----------------
// grid (NB, 8), block 128 (lane = 2 channels: t and t+128), 19.4 KB LDS.
// cam tile in LDS; each broadcast ds_read_b128 now feeds 128 channels (2/lane),
// halving LDS-pipe pressure vs 1 ch/lane. x is read as full 128 B line bursts
// (8 consecutive float4 per channel consumed immediately) so each line is
// fetched from L2/HBM exactly once — no L1-thrash re-fetch window.
__global__ __launch_bounds__(128, 3) void k_feat(const float* __restrict__ x,
                                                 const float* __restrict__ cam,
                                                 float* __restrict__ partial,
                                                 int nloop) {
    __shared__ float cams[KK * HWT];
    const int b = blockIdx.y;
    const int t = threadIdx.x;          // c0 = t, c1 = t + 128

    float acc0[KK], acc1[KK];
#pragma unroll
    for (int k = 0; k < KK; ++k) { acc0[k] = 0.f; acc1[k] = 0.f; }

    const float4* __restrict__ cs = reinterpret_cast<const float4*>(cams);

#pragma unroll 1
    for (int l = 0; l < nloop; ++l) {
        const int ch = blockIdx.x * nloop + l;
        const int hw0 = ch * HWT;

        // stage cam tile: 1216 float4, coalesced
        {
            const float4* cg = reinterpret_cast<const float4*>(cam + (size_t)b * KK * HWN + hw0);
            float4* cw = reinterpret_cast<float4*>(cams);
            for (int idx = t; idx < KK * (HWT / 4); idx += 128)
                cw[idx] = cg[(size_t)(idx >> 6) * (HWN / 4) + (idx & 63)];
        }
        __syncthreads();

        const float4* __restrict__ xr0 =
            reinterpret_cast<const float4*>(x + ((size_t)(b * CC + t)) * HWN + hw0);
        const float4* __restrict__ xr1 =
            reinterpret_cast<const float4*>(x + ((size_t)(b * CC + t + 128)) * HWN + hw0);

#pragma unroll 1
        for (int m = 0; m < HWT / 32; ++m) {      // 8 bursts of 32 hw
            float4 xv0[8], xv1[8];
#pragma unroll
            for (int u = 0; u < 8; ++u) xv0[u] = xr0[m * 8 + u];
#pragma unroll
            for (int u = 0; u < 8; ++u) xv1[u] = xr1[m * 8 + u];
#pragma unroll
            for (int j = 0; j < 8; ++j) {
                const int i = m * 8 + j;
#pragma unroll
                for (int k = 0; k < KK; ++k) {
                    const float4 cv = cs[k * (HWT / 4) + i];   // broadcast read
                    acc0[k] = fmaf(xv0[j].w, cv.w, fmaf(xv0[j].z, cv.z,
                              fmaf(xv0[j].y, cv.y, fmaf(xv0[j].x, cv.x, acc0[k]))));
                    acc1[k] = fmaf(xv1[j].w, cv.w, fmaf(xv1[j].z, cv.z,
                              fmaf(xv1[j].y, cv.y, fmaf(xv1[j].x, cv.x, acc1[k]))));
                }
            }
        }
        __syncthreads();   // tile consumed before next overwrite
    }

    float* pb = partial + (size_t)blockIdx.x * (BB * KK * CC) + (size_t)(b * KK) * CC;
#pragma unroll
    for (int k = 0; k < KK; ++k) {
        pb[(size_t)k * CC + t]       = acc0[k];
        pb[(size_t)k * CC + t + 128] = acc1[k];
    }
}

// ---------------- Stage 1b: feat = (1/HW) * sum_slices partial (direct store) ----------------
// grid (152), block 256. Block 0 also zeroes the scalar accumulators.
__global__ __launch_bounds__(256) void k_reduce(const float* __restrict__ partial,
                                                float* __restrict__ feat,
                                                float* __restrict__ scal, int nb) {
    const int o = blockIdx.x * 256 + threadIdx.x;     // 0..38911
    if (blockIdx.x == 0 && threadIdx.x < 16) scal[threadIdx.x] = 0.f;
    float s = 0.f;
#pragma unroll 8
    for (int i = 0; i < nb; ++i)
        s += partial[(size_t)i * (BB * KK * CC) + o];
    feat[o] = s * (1.0f / (float)HWN);
}

// ---------------- Stage 2a: h1 = lrelu(feat @ W1 + b1), 2 rows/block ----------------
// grid (8, 76), block 256
__global__ __launch_bounds__(256) void k_mlp1(const float* __restrict__ feat,
                                              const float* __restrict__ W1,
                                              const float* __restrict__ b1,
                                              float* __restrict__ h1) {
    const int r0 = blockIdx.y * 2;
    const int j = blockIdx.x * 256 + threadIdx.x;
    const float4* __restrict__ f0 = reinterpret_cast<const float4*>(feat + (size_t)r0 * CC);
    const float4* __restrict__ f1 = reinterpret_cast<const float4*>(feat + (size_t)(r0 + 1) * CC);

    const float bias = b1[j];
    float a0 = bias, a1 = bias;
#pragma unroll 8
    for (int c4 = 0; c4 < CC / 4; ++c4) {
        const float4 v0 = f0[c4], v1 = f1[c4];
        const size_t cb = (size_t)(c4 * 4) * H1 + j;
        const float w0 = W1[cb], w1 = W1[cb + H1], w2 = W1[cb + 2 * H1], w3 = W1[cb + 3 * H1];
        a0 = fmaf(v0.x, w0, a0); a0 = fmaf(v0.y, w1, a0); a0 = fmaf(v0.z, w2, a0); a0 = fmaf(v0.w, w3, a0);
        a1 = fmaf(v1.x, w0, a1); a1 = fmaf(v1.y, w1, a1); a1 = fmaf(v1.z, w2, a1); a1 = fmaf(v1.w, w3, a1);
    }
    h1[(size_t)r0 * H1 + j]       = a0 > 0.f ? a0 : NEG * a0;
    h1[(size_t)(r0 + 1) * H1 + j] = a1 > 0.f ? a1 : NEG * a1;
}

// ---------------- Stage 2b: h2 = lrelu(h1 @ W2 + b2), 2 rows/block ----------------
// grid (4, 76), block 128
__global__ __launch_bounds__(128) void k_mlp2(const float* __restrict__ h1,
                                              const float* __restrict__ W2,
                                              const float* __restrict__ b2,
                                              float* __restrict__ h2) {
    const int r0 = blockIdx.y * 2;
    const int j = blockIdx.x * 128 + threadIdx.x;
    const float4* __restrict__ f0 = reinterpret_cast<const float4*>(h1 + (size_t)r0 * H1);
    const float4* __restrict__ f1 = reinterpret_cast<const float4*>(h1 + (size_t)(r0 + 1) * H1);

    const float bias = b2[j];
    float a0 = bias, a1 = bias;
#pragma unroll 8
    for (int c4 = 0; c4 < H1 / 4; ++c4) {
        const float4 v0 = f0[c4], v1 = f1[c4];
        const size_t cb = (size_t)(c4 * 4) * H2 + j;
        const float w0 = W2[cb], w1 = W2[cb + H2], w2 = W2[cb + 2 * H2], w3 = W2[cb + 3 * H2];
        a0 = fmaf(v0.x, w0, a0); a0 = fmaf(v0.y, w1, a0); a0 = fmaf(v0.z, w2, a0); a0 = fmaf(v0.w, w3, a0);
        a1 = fmaf(v1.x, w0, a1); a1 = fmaf(v1.y, w1, a1); a1 = fmaf(v1.z, w2, a1); a1 = fmaf(v1.w, w3, a1);
    }
    h2[(size_t)r0 * H2 + j]       = a0 > 0.f ? a0 : NEG * a0;
    h2[(size_t)(r0 + 1) * H2 + j] = a1 > 0.f ? a1 : NEG * a1;
}

// ---------------- Stage 3: logits + CE loss + masked reductions ----------------
__global__ __launch_bounds__(768) void k_loss(const float* __restrict__ h2,
                                              const float* __restrict__ Wc,
                                              const float* __restrict__ bc,
                                              const int* __restrict__ gt,
                                              const float* __restrict__ gt_src,
                                              const float* __restrict__ gt_tgt,
                                              const float* __restrict__ wts,
                                              float* __restrict__ scal) {
    __shared__ float h2s[KK][H2];
    __shared__ float lg[KK][NC];
    __shared__ float rloss[KK], rmask[KK], rlbl[KK], rmatch[KK];

    const int b = blockIdx.x;
    const int t = threadIdx.x;

    const float* src = h2 + (size_t)b * KK * H2;
    for (int i = t; i < KK * H2; i += 768) ((float*)h2s)[i] = src[i];
    __syncthreads();

    if (t < KK * NC) {
        const int k = t / NC, j = t % NC;
        float acc = bc[j];
        for (int c = 0; c < H2; ++c) acc = fmaf(h2s[k][c], Wc[(size_t)c * NC + j], acc);
        lg[k][j] = acc;
    }
    __syncthreads();

    if (t < KK) {
        const int k = t;
        float m = -1e30f; int am = 0;
        for (int j = 0; j < NC; ++j) {
            float v = lg[k][j];
            if (v > m) { m = v; am = j; }
        }
        float se = 0.f, celbl = 0.f, lsum = 0.f, lm = -1e30f; int al = 0;
        for (int j = 0; j < NC; ++j) {
            float v = lg[k][j];
            se += expf(v - m);
            float lb = (j < KK) ? gt_src[((size_t)b * KK + k) * KK + j]
                                : gt_tgt[((size_t)b * KK + k) * KK + (j - KK)];
            celbl = fmaf(lb, v, celbl);
            lsum += lb;
            if (lb > lm) { lm = lb; al = j; }
        }
        float lse = m + logf(se);
        float ce = lse * lsum - celbl;
        float mask = (gt[b * KK + k] > 0) ? 1.f : 0.f;
        rloss[k]  = mask * wts[b * KK + k] * ce;
        rmask[k]  = mask;
        rlbl[k]   = mask * lsum;
        rmatch[k] = mask * ((am == al) ? 1.f : 0.f);
    }
    __syncthreads();

    if (t == 0) {
        float n = 0.f, sl = 0.f, ls = 0.f, mt = 0.f;
        for (int k = 0; k < KK; ++k) { n += rmask[k]; sl += rloss[k]; ls += rlbl[k]; mt += rmatch[k]; }
        float sample_loss = sl / fmaxf(n, 1.f);
        bool valid = ls > 0.f;
        atomicAdd(&scal[0], valid ? sample_loss : 0.f);
        atomicAdd(&scal[1], valid ? mt : 0.f);
        atomicAdd(&scal[2], valid ? ls : 0.f);
    }
}

__global__ void k_final(const float* __restrict__ scal, float* __restrict__ out) {
    out[0] = scal[0] / (float)BB;
    out[1] = scal[1] / scal[2] * 100.f;
}

extern "C" void kernel_launch(void* const* d_in, const int* in_sizes, int n_in,
                              void* d_out, int out_size, void* d_ws, size_t ws_size,
                              hipStream_t stream) {
    const float* x      = (const float*)d_in[0];
    const float* cam    = (const float*)d_in[1];
    const int*   gt     = (const int*)d_in[2];
    const float* gt_src = (const float*)d_in[3];
    const float* gt_tgt = (const float*)d_in[4];
    const float* wts    = (const float*)d_in[5];
    const float* W1     = (const float*)d_in[6];
    const float* b1     = (const float*)d_in[7];
    const float* W2     = (const float*)d_in[8];
    const float* b2     = (const float*)d_in[9];
    const float* Wc     = (const float*)d_in[10];
    const float* bc     = (const float*)d_in[11];

    const size_t FEAT = (size_t)BB * KK * CC;         // 38912
    int NB = NCHUNK;
    while (NB > 8) {
        size_t need = (16 + FEAT + (size_t)152 * H1 + (size_t)152 * H2 + (size_t)NB * FEAT) * 4;
        if (need <= ws_size) break;
        NB >>= 1;
    }
    const int nloop = NCHUNK / NB;

    float* ws      = (float*)d_ws;
    float* scal    = ws;                               // 16 floats
    float* feat    = ws + 16;                          // 38912
    float* h1      = feat + FEAT;                      // 152*2048
    float* h2      = h1 + (size_t)152 * H1;            // 152*512
    float* partial = h2 + (size_t)152 * H2;            // NB*38912

    dim3 g1(NB, BB);
    k_feat<<<g1, 128, 0, stream>>>(x, cam, partial, nloop);
    k_reduce<<<152, 256, 0, stream>>>(partial, feat, scal, NB);
    dim3 g2(H1 / 256, 76);
    k_mlp1<<<g2, 256, 0, stream>>>(feat, W1, b1, h1);
    dim3 g3(H2 / 128, 76);
    k_mlp2<<<g3, 128, 0, stream>>>(h1, W2, b2, h2);
    k_loss<<<BB, 768, 0, stream>>>(h2, Wc, bc, gt, gt_src, gt_tgt, wts, scal);
    k_final<<<1, 1, 0, stream>>>(scal, (float*)d_out);
}

// Round 6
// 860.554 us; speedup vs baseline: 1.0380x; 1.0380x over previous
//
#include <hip/hip_runtime.h>

#define BB 8
#define CC 256
#define KK 19
#define HWN 65536
#define H1 2048
#define H2 512
#define NC 38
#define NEG 0.2f
#define HWT 256            // hw per chunk (cam tile = 19*256*4 = 19456 B LDS)
#define NCHUNK 256         // chunks per image (HWN / HWT)

// ---------------- Stage 1: partial[slice][b][k][c] = sum_{hw in slice} cam*x ----------------
// grid (NB, 8), block 256 (thread = channel). cam tile in LDS (uniform
// broadcast reads). x consumed in full-128B-line bursts: 8 float4 loaded to
// registers back-to-back, then immediately used -> each line fetched once
// (kills R4's L1 thrash). Live state: acc[19]+xv[8] ~ 70 VGPR; cap (256,5)
// leaves headroom so no scratch spill (R2/R5 lesson).
__global__ __launch_bounds__(256, 5) void k_feat(const float* __restrict__ x,
                                                 const float* __restrict__ cam,
                                                 float* __restrict__ partial,
                                                 int nloop) {
    __shared__ float cams[KK * HWT];
    const int b = blockIdx.y;
    const int t = threadIdx.x;

    float acc[KK];
#pragma unroll
    for (int k = 0; k < KK; ++k) acc[k] = 0.f;

    const float4* __restrict__ cs = reinterpret_cast<const float4*>(cams);

#pragma unroll 1
    for (int l = 0; l < nloop; ++l) {
        const int ch = blockIdx.x * nloop + l;
        const int hw0 = ch * HWT;

        // stage cam tile: 1216 float4, coalesced
        {
            const float4* cg = reinterpret_cast<const float4*>(cam + (size_t)b * KK * HWN + hw0);
            float4* cw = reinterpret_cast<float4*>(cams);
            for (int idx = t; idx < KK * (HWT / 4); idx += 256)
                cw[idx] = cg[(size_t)(idx >> 6) * (HWN / 4) + (idx & 63)];
        }
        __syncthreads();

        const float4* __restrict__ xr =
            reinterpret_cast<const float4*>(x + ((size_t)(b * CC + t)) * HWN + hw0);

#pragma unroll 1
        for (int m = 0; m < HWT / 32; ++m) {      // 8 bursts of 32 hw
            float4 xv[8];                          // one full 128B line
#pragma unroll
            for (int u = 0; u < 8; ++u) xv[u] = xr[m * 8 + u];
#pragma unroll
            for (int u = 0; u < 8; ++u) {
                const int i = m * 8 + u;
#pragma unroll
                for (int k = 0; k < KK; ++k) {
                    const float4 cv = cs[k * (HWT / 4) + i];   // broadcast read
                    acc[k] = fmaf(xv[u].w, cv.w, fmaf(xv[u].z, cv.z,
                             fmaf(xv[u].y, cv.y, fmaf(xv[u].x, cv.x, acc[k]))));
                }
            }
        }
        __syncthreads();   // tile consumed before next overwrite
    }

    float* pb = partial + (size_t)blockIdx.x * (BB * KK * CC) + (size_t)(b * KK) * CC + t;
#pragma unroll
    for (int k = 0; k < KK; ++k) pb[(size_t)k * CC] = acc[k];
}

// ---------------- Stage 1b: feat = (1/HW) * sum_slices partial (direct store) ----------------
// grid (152), block 256. Block 0 also zeroes the scalar accumulators.
__global__ __launch_bounds__(256) void k_reduce(const float* __restrict__ partial,
                                                float* __restrict__ feat,
                                                float* __restrict__ scal, int nb) {
    const int o = blockIdx.x * 256 + threadIdx.x;     // 0..38911
    if (blockIdx.x == 0 && threadIdx.x < 16) scal[threadIdx.x] = 0.f;
    float s = 0.f;
#pragma unroll 8
    for (int i = 0; i < nb; ++i)
        s += partial[(size_t)i * (BB * KK * CC) + o];
    feat[o] = s * (1.0f / (float)HWN);
}

// ---------------- Stage 2a: h1 = lrelu(feat @ W1 + b1), 2 rows/block ----------------
// grid (8, 76), block 256
__global__ __launch_bounds__(256) void k_mlp1(const float* __restrict__ feat,
                                              const float* __restrict__ W1,
                                              const float* __restrict__ b1,
                                              float* __restrict__ h1) {
    const int r0 = blockIdx.y * 2;
    const int j = blockIdx.x * 256 + threadIdx.x;
    const float4* __restrict__ f0 = reinterpret_cast<const float4*>(feat + (size_t)r0 * CC);
    const float4* __restrict__ f1 = reinterpret_cast<const float4*>(feat + (size_t)(r0 + 1) * CC);

    const float bias = b1[j];
    float a0 = bias, a1 = bias;
#pragma unroll 8
    for (int c4 = 0; c4 < CC / 4; ++c4) {
        const float4 v0 = f0[c4], v1 = f1[c4];
        const size_t cb = (size_t)(c4 * 4) * H1 + j;
        const float w0 = W1[cb], w1 = W1[cb + H1], w2 = W1[cb + 2 * H1], w3 = W1[cb + 3 * H1];
        a0 = fmaf(v0.x, w0, a0); a0 = fmaf(v0.y, w1, a0); a0 = fmaf(v0.z, w2, a0); a0 = fmaf(v0.w, w3, a0);
        a1 = fmaf(v1.x, w0, a1); a1 = fmaf(v1.y, w1, a1); a1 = fmaf(v1.z, w2, a1); a1 = fmaf(v1.w, w3, a1);
    }
    h1[(size_t)r0 * H1 + j]       = a0 > 0.f ? a0 : NEG * a0;
    h1[(size_t)(r0 + 1) * H1 + j] = a1 > 0.f ? a1 : NEG * a1;
}

// ---------------- Stage 2b: h2 = lrelu(h1 @ W2 + b2), 2 rows/block ----------------
// grid (4, 76), block 128
__global__ __launch_bounds__(128) void k_mlp2(const float* __restrict__ h1,
                                              const float* __restrict__ W2,
                                              const float* __restrict__ b2,
                                              float* __restrict__ h2) {
    const int r0 = blockIdx.y * 2;
    const int j = blockIdx.x * 128 + threadIdx.x;
    const float4* __restrict__ f0 = reinterpret_cast<const float4*>(h1 + (size_t)r0 * H1);
    const float4* __restrict__ f1 = reinterpret_cast<const float4*>(h1 + (size_t)(r0 + 1) * H1);

    const float bias = b2[j];
    float a0 = bias, a1 = bias;
#pragma unroll 8
    for (int c4 = 0; c4 < H1 / 4; ++c4) {
        const float4 v0 = f0[c4], v1 = f1[c4];
        const size_t cb = (size_t)(c4 * 4) * H2 + j;
        const float w0 = W2[cb], w1 = W2[cb + H2], w2 = W2[cb + 2 * H2], w3 = W2[cb + 3 * H2];
        a0 = fmaf(v0.x, w0, a0); a0 = fmaf(v0.y, w1, a0); a0 = fmaf(v0.z, w2, a0); a0 = fmaf(v0.w, w3, a0);
        a1 = fmaf(v1.x, w0, a1); a1 = fmaf(v1.y, w1, a1); a1 = fmaf(v1.z, w2, a1); a1 = fmaf(v1.w, w3, a1);
    }
    h2[(size_t)r0 * H2 + j]       = a0 > 0.f ? a0 : NEG * a0;
    h2[(size_t)(r0 + 1) * H2 + j] = a1 > 0.f ? a1 : NEG * a1;
}

// ---------------- Stage 3: logits + CE loss + masked reductions ----------------
__global__ __launch_bounds__(768) void k_loss(const float* __restrict__ h2,
                                              const float* __restrict__ Wc,
                                              const float* __restrict__ bc,
                                              const int* __restrict__ gt,
                                              const float* __restrict__ gt_src,
                                              const float* __restrict__ gt_tgt,
                                              const float* __restrict__ wts,
                                              float* __restrict__ scal) {
    __shared__ float h2s[KK][H2];
    __shared__ float lg[KK][NC];
    __shared__ float rloss[KK], rmask[KK], rlbl[KK], rmatch[KK];

    const int b = blockIdx.x;
    const int t = threadIdx.x;

    const float* src = h2 + (size_t)b * KK * H2;
    for (int i = t; i < KK * H2; i += 768) ((float*)h2s)[i] = src[i];
    __syncthreads();

    if (t < KK * NC) {
        const int k = t / NC, j = t % NC;
        float acc = bc[j];
        for (int c = 0; c < H2; ++c) acc = fmaf(h2s[k][c], Wc[(size_t)c * NC + j], acc);
        lg[k][j] = acc;
    }
    __syncthreads();

    if (t < KK) {
        const int k = t;
        float m = -1e30f; int am = 0;
        for (int j = 0; j < NC; ++j) {
            float v = lg[k][j];
            if (v > m) { m = v; am = j; }
        }
        float se = 0.f, celbl = 0.f, lsum = 0.f, lm = -1e30f; int al = 0;
        for (int j = 0; j < NC; ++j) {
            float v = lg[k][j];
            se += expf(v - m);
            float lb = (j < KK) ? gt_src[((size_t)b * KK + k) * KK + j]
                                : gt_tgt[((size_t)b * KK + k) * KK + (j - KK)];
            celbl = fmaf(lb, v, celbl);
            lsum += lb;
            if (lb > lm) { lm = lb; al = j; }
        }
        float lse = m + logf(se);
        float ce = lse * lsum - celbl;
        float mask = (gt[b * KK + k] > 0) ? 1.f : 0.f;
        rloss[k]  = mask * wts[b * KK + k] * ce;
        rmask[k]  = mask;
        rlbl[k]   = mask * lsum;
        rmatch[k] = mask * ((am == al) ? 1.f : 0.f);
    }
    __syncthreads();

    if (t == 0) {
        float n = 0.f, sl = 0.f, ls = 0.f, mt = 0.f;
        for (int k = 0; k < KK; ++k) { n += rmask[k]; sl += rloss[k]; ls += rlbl[k]; mt += rmatch[k]; }
        float sample_loss = sl / fmaxf(n, 1.f);
        bool valid = ls > 0.f;
        atomicAdd(&scal[0], valid ? sample_loss : 0.f);
        atomicAdd(&scal[1], valid ? mt : 0.f);
        atomicAdd(&scal[2], valid ? ls : 0.f);
    }
}

__global__ void k_final(const float* __restrict__ scal, float* __restrict__ out) {
    out[0] = scal[0] / (float)BB;
    out[1] = scal[1] / scal[2] * 100.f;
}

extern "C" void kernel_launch(void* const* d_in, const int* in_sizes, int n_in,
                              void* d_out, int out_size, void* d_ws, size_t ws_size,
                              hipStream_t stream) {
    const float* x      = (const float*)d_in[0];
    const float* cam    = (const float*)d_in[1];
    const int*   gt     = (const int*)d_in[2];
    const float* gt_src = (const float*)d_in[3];
    const float* gt_tgt = (const float*)d_in[4];
    const float* wts    = (const float*)d_in[5];
    const float* W1     = (const float*)d_in[6];
    const float* b1     = (const float*)d_in[7];
    const float* W2     = (const float*)d_in[8];
    const float* b2     = (const float*)d_in[9];
    const float* Wc     = (const float*)d_in[10];
    const float* bc     = (const float*)d_in[11];

    const size_t FEAT = (size_t)BB * KK * CC;         // 38912
    int NB = NCHUNK;
    while (NB > 8) {
        size_t need = (16 + FEAT + (size_t)152 * H1 + (size_t)152 * H2 + (size_t)NB * FEAT) * 4;
        if (need <= ws_size) break;
        NB >>= 1;
    }
    const int nloop = NCHUNK / NB;

    float* ws      = (float*)d_ws;
    float* scal    = ws;                               // 16 floats
    float* feat    = ws + 16;                          // 38912
    float* h1      = feat + FEAT;                      // 152*2048
    float* h2      = h1 + (size_t)152 * H1;            // 152*512
    float* partial = h2 + (size_t)152 * H2;            // NB*38912

    dim3 g1(NB, BB);
    k_feat<<<g1, 256, 0, stream>>>(x, cam, partial, nloop);
    k_reduce<<<152, 256, 0, stream>>>(partial, feat, scal, NB);
    dim3 g2(H1 / 256, 76);
    k_mlp1<<<g2, 256, 0, stream>>>(feat, W1, b1, h1);
    dim3 g3(H2 / 128, 76);
    k_mlp2<<<g3, 128, 0, stream>>>(h1, W2, b2, h2);
    k_loss<<<BB, 768, 0, stream>>>(h2, Wc, bc, gt, gt_src, gt_tgt, wts, scal);
    k_final<<<1, 1, 0, stream>>>(scal, (float*)d_out);
}

// Round 7
// 400.531 us; speedup vs baseline: 2.2303x; 2.1485x over previous
//
#include <hip/hip_runtime.h>

#define BB 8
#define CC 256
#define KK 19
#define HWN 65536
#define H1 2048
#define H2 512
#define NC 38
#define NEG 0.2f
#define NSL 8              // hw slices
#define HWS (HWN / NSL)    // 8192 hw per slice

// ---------------- Stage 1: partial[sl][b][k][c] = sum_{hw in slice} cam*x ----------------
// grid (32*NSL, 8), block 256 = 4 waves. Block covers 8 channels x one 8192-hw
// slice; wave w owns k in [5w, min(5w+5,19)). Lanes walk hw contiguously:
// each load instr = 64 lanes x 16 B = 1 KB contiguous (full lines, all L2
// channels) -- fixes the 256KB-stride channel-hot-spot + 4x sub-line refetch
// seen in R6 (FETCH 2.1 GB). No LDS, no barriers. acc[5][8] statically
// indexed (guarded full unroll, rule #20); ~90 VGPR, cap 128.
__global__ __launch_bounds__(256, 4) void k_feat(const float* __restrict__ x,
                                                 const float* __restrict__ cam,
                                                 float* __restrict__ partial) {
    const int b  = blockIdx.y;
    const int cg = blockIdx.x & 31;        // channel group -> c0 = 8*cg
    const int sl = blockIdx.x >> 5;        // hw slice
    const int w  = threadIdx.x >> 6;       // wave id 0..3
    const int l  = threadIdx.x & 63;       // lane
    const int c0 = cg * 8;
    const int k0 = w * 5;                  // k base (wave 3: 4 k's)

    const float4* __restrict__ x4 = reinterpret_cast<const float4*>(x);
    const float4* __restrict__ c4 = reinterpret_cast<const float4*>(cam);

    float acc[5][8];
#pragma unroll
    for (int kk = 0; kk < 5; ++kk)
#pragma unroll
        for (int c = 0; c < 8; ++c) acc[kk][c] = 0.f;

    const int hwb = sl * (HWS / 4);        // float4 base of slice

#pragma unroll 1
    for (int it = 0; it < HWS / 256; ++it) {      // 32 iterations
        const int hw4 = hwb + it * 64 + l;
        float4 xv[8];
#pragma unroll
        for (int c = 0; c < 8; ++c)
            xv[c] = x4[(size_t)(b * CC + c0 + c) * (HWN / 4) + hw4];
#pragma unroll
        for (int kk = 0; kk < 5; ++kk) {
            if (k0 + kk < KK) {                   // wave-uniform guard
                const float4 cv = c4[(size_t)(b * KK + k0 + kk) * (HWN / 4) + hw4];
#pragma unroll
                for (int c = 0; c < 8; ++c)
                    acc[kk][c] = fmaf(xv[c].w, cv.w, fmaf(xv[c].z, cv.z,
                                 fmaf(xv[c].y, cv.y, fmaf(xv[c].x, cv.x, acc[kk][c]))));
            }
        }
    }

    // butterfly wave-reduce each (k,c), lane 0 stores per-slice partial
#pragma unroll
    for (int kk = 0; kk < 5; ++kk) {
        if (k0 + kk < KK) {
#pragma unroll
            for (int c = 0; c < 8; ++c) {
                float v = acc[kk][c];
#pragma unroll
                for (int off = 32; off; off >>= 1) v += __shfl_xor(v, off, 64);
                if (l == 0)
                    partial[(size_t)sl * (BB * KK * CC) +
                            (size_t)(b * KK + k0 + kk) * CC + c0 + c] = v;
            }
        }
    }
}

// ---------------- Stage 1b: feat = (1/HW) * sum_slices partial ----------------
// grid (152), block 256. Block 0 also zeroes the scalar accumulators.
__global__ __launch_bounds__(256) void k_reduce(const float* __restrict__ partial,
                                                float* __restrict__ feat,
                                                float* __restrict__ scal, int nb) {
    const int o = blockIdx.x * 256 + threadIdx.x;     // 0..38911
    if (blockIdx.x == 0 && threadIdx.x < 16) scal[threadIdx.x] = 0.f;
    float s = 0.f;
#pragma unroll 8
    for (int i = 0; i < nb; ++i)
        s += partial[(size_t)i * (BB * KK * CC) + o];
    feat[o] = s * (1.0f / (float)HWN);
}

// ---------------- Stage 2a: h1 = lrelu(feat @ W1 + b1), 2 rows/block ----------------
// grid (8, 76), block 256
__global__ __launch_bounds__(256) void k_mlp1(const float* __restrict__ feat,
                                              const float* __restrict__ W1,
                                              const float* __restrict__ b1,
                                              float* __restrict__ h1) {
    const int r0 = blockIdx.y * 2;
    const int j = blockIdx.x * 256 + threadIdx.x;
    const float4* __restrict__ f0 = reinterpret_cast<const float4*>(feat + (size_t)r0 * CC);
    const float4* __restrict__ f1 = reinterpret_cast<const float4*>(feat + (size_t)(r0 + 1) * CC);

    const float bias = b1[j];
    float a0 = bias, a1 = bias;
#pragma unroll 8
    for (int c4 = 0; c4 < CC / 4; ++c4) {
        const float4 v0 = f0[c4], v1 = f1[c4];
        const size_t cb = (size_t)(c4 * 4) * H1 + j;
        const float w0 = W1[cb], w1 = W1[cb + H1], w2 = W1[cb + 2 * H1], w3 = W1[cb + 3 * H1];
        a0 = fmaf(v0.x, w0, a0); a0 = fmaf(v0.y, w1, a0); a0 = fmaf(v0.z, w2, a0); a0 = fmaf(v0.w, w3, a0);
        a1 = fmaf(v1.x, w0, a1); a1 = fmaf(v1.y, w1, a1); a1 = fmaf(v1.z, w2, a1); a1 = fmaf(v1.w, w3, a1);
    }
    h1[(size_t)r0 * H1 + j]       = a0 > 0.f ? a0 : NEG * a0;
    h1[(size_t)(r0 + 1) * H1 + j] = a1 > 0.f ? a1 : NEG * a1;
}

// ---------------- Stage 2b: h2 = lrelu(h1 @ W2 + b2), 2 rows/block ----------------
// grid (4, 76), block 128
__global__ __launch_bounds__(128) void k_mlp2(const float* __restrict__ h1,
                                              const float* __restrict__ W2,
                                              const float* __restrict__ b2,
                                              float* __restrict__ h2) {
    const int r0 = blockIdx.y * 2;
    const int j = blockIdx.x * 128 + threadIdx.x;
    const float4* __restrict__ f0 = reinterpret_cast<const float4*>(h1 + (size_t)r0 * H1);
    const float4* __restrict__ f1 = reinterpret_cast<const float4*>(h1 + (size_t)(r0 + 1) * H1);

    const float bias = b2[j];
    float a0 = bias, a1 = bias;
#pragma unroll 8
    for (int c4 = 0; c4 < H1 / 4; ++c4) {
        const float4 v0 = f0[c4], v1 = f1[c4];
        const size_t cb = (size_t)(c4 * 4) * H2 + j;
        const float w0 = W2[cb], w1 = W2[cb + H2], w2 = W2[cb + 2 * H2], w3 = W2[cb + 3 * H2];
        a0 = fmaf(v0.x, w0, a0); a0 = fmaf(v0.y, w1, a0); a0 = fmaf(v0.z, w2, a0); a0 = fmaf(v0.w, w3, a0);
        a1 = fmaf(v1.x, w0, a1); a1 = fmaf(v1.y, w1, a1); a1 = fmaf(v1.z, w2, a1); a1 = fmaf(v1.w, w3, a1);
    }
    h2[(size_t)r0 * H2 + j]       = a0 > 0.f ? a0 : NEG * a0;
    h2[(size_t)(r0 + 1) * H2 + j] = a1 > 0.f ? a1 : NEG * a1;
}

// ---------------- Stage 3: logits + CE loss + masked reductions ----------------
__global__ __launch_bounds__(768) void k_loss(const float* __restrict__ h2,
                                              const float* __restrict__ Wc,
                                              const float* __restrict__ bc,
                                              const int* __restrict__ gt,
                                              const float* __restrict__ gt_src,
                                              const float* __restrict__ gt_tgt,
                                              const float* __restrict__ wts,
                                              float* __restrict__ scal) {
    __shared__ float h2s[KK][H2];
    __shared__ float lg[KK][NC];
    __shared__ float rloss[KK], rmask[KK], rlbl[KK], rmatch[KK];

    const int b = blockIdx.x;
    const int t = threadIdx.x;

    const float* src = h2 + (size_t)b * KK * H2;
    for (int i = t; i < KK * H2; i += 768) ((float*)h2s)[i] = src[i];
    __syncthreads();

    if (t < KK * NC) {
        const int k = t / NC, j = t % NC;
        float acc = bc[j];
        for (int c = 0; c < H2; ++c) acc = fmaf(h2s[k][c], Wc[(size_t)c * NC + j], acc);
        lg[k][j] = acc;
    }
    __syncthreads();

    if (t < KK) {
        const int k = t;
        float m = -1e30f; int am = 0;
        for (int j = 0; j < NC; ++j) {
            float v = lg[k][j];
            if (v > m) { m = v; am = j; }
        }
        float se = 0.f, celbl = 0.f, lsum = 0.f, lm = -1e30f; int al = 0;
        for (int j = 0; j < NC; ++j) {
            float v = lg[k][j];
            se += expf(v - m);
            float lb = (j < KK) ? gt_src[((size_t)b * KK + k) * KK + j]
                                : gt_tgt[((size_t)b * KK + k) * KK + (j - KK)];
            celbl = fmaf(lb, v, celbl);
            lsum += lb;
            if (lb > lm) { lm = lb; al = j; }
        }
        float lse = m + logf(se);
        float ce = lse * lsum - celbl;
        float mask = (gt[b * KK + k] > 0) ? 1.f : 0.f;
        rloss[k]  = mask * wts[b * KK + k] * ce;
        rmask[k]  = mask;
        rlbl[k]   = mask * lsum;
        rmatch[k] = mask * ((am == al) ? 1.f : 0.f);
    }
    __syncthreads();

    if (t == 0) {
        float n = 0.f, sl = 0.f, ls = 0.f, mt = 0.f;
        for (int k = 0; k < KK; ++k) { n += rmask[k]; sl += rloss[k]; ls += rlbl[k]; mt += rmatch[k]; }
        float sample_loss = sl / fmaxf(n, 1.f);
        bool valid = ls > 0.f;
        atomicAdd(&scal[0], valid ? sample_loss : 0.f);
        atomicAdd(&scal[1], valid ? mt : 0.f);
        atomicAdd(&scal[2], valid ? ls : 0.f);
    }
}

__global__ void k_final(const float* __restrict__ scal, float* __restrict__ out) {
    out[0] = scal[0] / (float)BB;
    out[1] = scal[1] / scal[2] * 100.f;
}

extern "C" void kernel_launch(void* const* d_in, const int* in_sizes, int n_in,
                              void* d_out, int out_size, void* d_ws, size_t ws_size,
                              hipStream_t stream) {
    const float* x      = (const float*)d_in[0];
    const float* cam    = (const float*)d_in[1];
    const int*   gt     = (const int*)d_in[2];
    const float* gt_src = (const float*)d_in[3];
    const float* gt_tgt = (const float*)d_in[4];
    const float* wts    = (const float*)d_in[5];
    const float* W1     = (const float*)d_in[6];
    const float* b1     = (const float*)d_in[7];
    const float* W2     = (const float*)d_in[8];
    const float* b2     = (const float*)d_in[9];
    const float* Wc     = (const float*)d_in[10];
    const float* bc     = (const float*)d_in[11];

    const size_t FEAT = (size_t)BB * KK * CC;          // 38912
    float* ws      = (float*)d_ws;
    float* scal    = ws;                               // 16 floats
    float* feat    = ws + 16;                          // 38912
    float* h1      = feat + FEAT;                      // 152*2048
    float* h2      = h1 + (size_t)152 * H1;            // 152*512
    float* partial = h2 + (size_t)152 * H2;            // NSL*38912 = 1.2 MB

    dim3 g1(32 * NSL, BB);                             // 2048 blocks
    k_feat<<<g1, 256, 0, stream>>>(x, cam, partial);
    k_reduce<<<152, 256, 0, stream>>>(partial, feat, scal, NSL);
    dim3 g2(H1 / 256, 76);
    k_mlp1<<<g2, 256, 0, stream>>>(feat, W1, b1, h1);
    dim3 g3(H2 / 128, 76);
    k_mlp2<<<g3, 128, 0, stream>>>(h1, W2, b2, h2);
    k_loss<<<BB, 768, 0, stream>>>(h2, Wc, bc, gt, gt_src, gt_tgt, wts, scal);
    k_final<<<1, 1, 0, stream>>>(scal, (float*)d_out);
}